// Round 7
// baseline (423.560 us; speedup 1.0000x reference)
//
#include <hip/hip_runtime.h>
#include <math.h>

// Problem constants
constexpr int CB = 4, CN = 1024, CT = 3, CR = 4, CH = 8, CDK = 32, COUT = 256;

typedef __attribute__((ext_vector_type(4))) float f32x4;
typedef __attribute__((ext_vector_type(8))) short s16x8;
typedef __attribute__((ext_vector_type(2))) _Float16 f16x2;
typedef __attribute__((ext_vector_type(4))) _Float16 f16x4;
typedef __attribute__((ext_vector_type(8))) _Float16 f16x8;
typedef __attribute__((ext_vector_type(4))) unsigned short u16x4;
typedef __attribute__((ext_vector_type(8))) unsigned short u16x8;

union W4 { f16x4 v4; f16x2 v2[2]; };

__device__ inline unsigned short f2bf(float x) {
    unsigned u = __float_as_uint(x);
    unsigned r = (u + 0x7fffu + ((u >> 16) & 1u)) >> 16;
    return (unsigned short)r;
}
__device__ inline float bf2f(unsigned short b) {
    return __uint_as_float(((unsigned)b) << 16);
}
__device__ inline f16x2 pk2(float a, float b) {
    auto t = __builtin_amdgcn_cvt_pkrtz(a, b);   // __fp16 ext_vector(2)
    f16x2 r;
    __builtin_memcpy(&r, &t, sizeof(r));
    return r;
}

// ---------------------------------------------------------------------------
// Fused independent prep work, partitioned by blockIdx.x:
// [0,1024)    splitx: nf -> bf16 hi/lo
// [1024,1792) wsplit: weight transpose + split (12 weight mats, 64 tiles each)
// [1792,1824) mT: rel_msg transpose to f16
// [1824,1840) zero rowsum
// [1840,5936) coef_t: coefT[b][j][i][r] = adj[b,i,j]*erel[b,i,j,r]
__global__ __launch_bounds__(256) void prep0(
    const float* __restrict__ nf,
    unsigned short* __restrict__ Xh, unsigned short* __restrict__ Xl,
    const float* __restrict__ Wq, const float* __restrict__ Wk,
    const float* __restrict__ Wv, const float* __restrict__ Wa,
    unsigned short* __restrict__ WTh, unsigned short* __restrict__ WTl,
    const float* __restrict__ rel_msg, _Float16* __restrict__ MT,
    float* __restrict__ rs,
    const float* __restrict__ adj, const float* __restrict__ erel,
    float* __restrict__ coefT)
{
    __shared__ float smem[32 * 132];
    const int bx = blockIdx.x, tid = threadIdx.x;
    if (bx < 1024) {
        size_t idx = ((size_t)bx * 256 + tid) * 4;
        f32x4 v = *(const f32x4*)(nf + idx);
        u16x4 hv, lv;
        #pragma unroll
        for (int k = 0; k < 4; ++k) {
            unsigned short hb = f2bf(v[k]);
            hv[k] = hb; lv[k] = f2bf(v[k] - bf2f(hb));
        }
        *(u16x4*)(Xh + idx) = hv;
        *(u16x4*)(Xl + idx) = lv;
    } else if (bx < 1792) {
        int w = bx - 1024;
        int zz = w >> 6; int rem = w & 63;
        int k0 = (rem >> 3) * 32, n0 = (rem & 7) * 32;
        int t = zz % 3;
        const float* W;
        if (zz < 9) { int w3 = zz / 3; W = (w3 == 0 ? Wq : (w3 == 1 ? Wk : Wv)); }
        else W = Wa;
        W += (size_t)t * COUT * COUT;
        {
            int k = tid >> 3, n4 = (tid & 7) * 4;
            f32x4 v = *(const f32x4*)(W + (size_t)(k0 + k) * COUT + n0 + n4);
            smem[(n4 + 0) * 33 + k] = v[0]; smem[(n4 + 1) * 33 + k] = v[1];
            smem[(n4 + 2) * 33 + k] = v[2]; smem[(n4 + 3) * 33 + k] = v[3];
        }
        __syncthreads();
        int n = tid >> 3, k4 = (tid & 7) * 4;
        u16x4 hv, lv;
        #pragma unroll
        for (int j = 0; j < 4; ++j) {
            float x = smem[n * 33 + k4 + j];
            unsigned short hb = f2bf(x);
            hv[j] = hb; lv[j] = f2bf(x - bf2f(hb));
        }
        size_t off = (size_t)zz * COUT * COUT + (size_t)(n0 + n) * COUT + k0 + k4;
        *(u16x4*)(WTh + off) = hv;
        *(u16x4*)(WTl + off) = lv;
    } else if (bx < 1824) {
        int rh = bx - 1792;
        int e = tid >> 3, ep4 = (tid & 7) * 4;
        f16x4 o;
        #pragma unroll
        for (int k = 0; k < 4; ++k)
            o[k] = (_Float16)rel_msg[((size_t)rh * 32 + ep4 + k) * 32 + e];
        *(f16x4*)(MT + ((size_t)rh * 32 + e) * 32 + ep4) = o;
    } else if (bx < 1840) {
        rs[(bx - 1824) * 256 + tid] = 0.f;
    } else {
        int c = bx - 1840;
        int b = c >> 10; int rem = c & 1023;
        int i0 = (rem >> 5) * 32; int j0 = (rem & 31) * 32;
        {
            int ii = tid >> 3, jc = tid & 7;
            size_t arow = ((size_t)b * CN + i0 + ii) * CN + j0;
            f32x4 av = *(const f32x4*)(adj + arow + jc * 4);
            #pragma unroll
            for (int kk = 0; kk < 4; ++kk) {
                int j = jc * 4 + kk;
                f32x4 ev = *(const f32x4*)(erel + (arow + j) * 4);
                float a = av[kk];
                f32x4 cv;
                cv[0] = ev[0] * a; cv[1] = ev[1] * a; cv[2] = ev[2] * a; cv[3] = ev[3] * a;
                *(f32x4*)&smem[j * 132 + ii * 4] = cv;
            }
        }
        __syncthreads();
        {
            int jj = tid >> 3, ic = tid & 7;
            size_t orow = ((size_t)b * CN + j0 + jj) * CN + i0;
            #pragma unroll
            for (int kk = 0; kk < 4; ++kk)
                *(f32x4*)(coefT + (orow + ic * 4 + kk) * 4) =
                    *(const f32x4*)&smem[jj * 132 + (ic * 4 + kk) * 4];
        }
    }
}

// ---------------------------------------------------------------------------
// bf16-split MFMA GEMM: Y[1024,256] = X[1024,256] @ W[256,256] + bias.
__global__ __launch_bounds__(256) void mfma_gemm(
    int mode,
    const unsigned short* __restrict__ Ah, const unsigned short* __restrict__ Al,
    const unsigned short* __restrict__ WTh, const unsigned short* __restrict__ WTl,
    const float* __restrict__ bq, const float* __restrict__ bk,
    const float* __restrict__ bv, const float* __restrict__ ba,
    float* __restrict__ Y0, float* __restrict__ Y1, float* __restrict__ Y2)
{
    int z = blockIdx.z;
    int b, t, widx;
    const float* bias;
    float* Y;
    if (mode == 0) {
        b = z / 9; int r9 = z % 9; int w3 = r9 / 3; t = r9 % 3;
        widx = w3 * 3 + t;
        bias = (w3 == 0 ? bq : (w3 == 1 ? bk : bv)) + t * COUT;
        Y = (w3 == 0 ? Y0 : (w3 == 1 ? Y1 : Y2)) + ((size_t)b * CT + t) * CN * COUT;
    } else {
        b = z / CT; t = z % CT;
        widx = 9 + t;
        bias = ba + t * COUT;
        Y = Y0 + ((size_t)b * CT + t) * CN * COUT;
    }
    const unsigned short* Ahb = Ah + (size_t)b * CN * COUT;
    const unsigned short* Alb = Al + (size_t)b * CN * COUT;
    const unsigned short* Bhb = WTh + (size_t)widx * COUT * COUT;
    const unsigned short* Blb = WTl + (size_t)widx * COUT * COUT;

    const int M0 = blockIdx.x * 128, N0 = blockIdx.y * 128;
    __shared__ unsigned short As[2][128][40];
    __shared__ unsigned short Bs[2][128][40];
    const int tid = threadIdx.x;
    const int wave = tid >> 6, lane = tid & 63;
    const int wm = wave & 1, wn = wave >> 1;
    const int col = lane & 15, quad = lane >> 4;

    f32x4 acc[4][4];
    #pragma unroll
    for (int mt = 0; mt < 4; ++mt)
        #pragma unroll
        for (int nt = 0; nt < 4; ++nt) acc[mt][nt] = (f32x4){0.f, 0.f, 0.f, 0.f};

    for (int kt = 0; kt < COUT; kt += 32) {
        #pragma unroll
        for (int q = 0; q < 2; ++q) {
            int f = q * 256 + tid;
            int m = f >> 2, kc = (f & 3) * 8;
            *(u16x8*)&As[0][m][kc] = *(const u16x8*)(Ahb + (size_t)(M0 + m) * COUT + kt + kc);
            *(u16x8*)&As[1][m][kc] = *(const u16x8*)(Alb + (size_t)(M0 + m) * COUT + kt + kc);
            *(u16x8*)&Bs[0][m][kc] = *(const u16x8*)(Bhb + (size_t)(N0 + m) * COUT + kt + kc);
            *(u16x8*)&Bs[1][m][kc] = *(const u16x8*)(Blb + (size_t)(N0 + m) * COUT + kt + kc);
        }
        __syncthreads();
        s16x8 ah[4], al4[4], bh[4], bl4[4];
        #pragma unroll
        for (int mt = 0; mt < 4; ++mt) {
            ah[mt]  = *(const s16x8*)&As[0][wm * 64 + mt * 16 + col][quad * 8];
            al4[mt] = *(const s16x8*)&As[1][wm * 64 + mt * 16 + col][quad * 8];
        }
        #pragma unroll
        for (int nt = 0; nt < 4; ++nt) {
            bh[nt]  = *(const s16x8*)&Bs[0][wn * 64 + nt * 16 + col][quad * 8];
            bl4[nt] = *(const s16x8*)&Bs[1][wn * 64 + nt * 16 + col][quad * 8];
        }
        #pragma unroll
        for (int mt = 0; mt < 4; ++mt)
            #pragma unroll
            for (int nt = 0; nt < 4; ++nt) {
                acc[mt][nt] = __builtin_amdgcn_mfma_f32_16x16x32_bf16(al4[mt], bh[nt], acc[mt][nt], 0, 0, 0);
                acc[mt][nt] = __builtin_amdgcn_mfma_f32_16x16x32_bf16(ah[mt], bl4[nt], acc[mt][nt], 0, 0, 0);
                acc[mt][nt] = __builtin_amdgcn_mfma_f32_16x16x32_bf16(ah[mt], bh[nt], acc[mt][nt], 0, 0, 0);
            }
        __syncthreads();
    }
    float bb[4];
    #pragma unroll
    for (int nt = 0; nt < 4; ++nt) bb[nt] = bias[N0 + wn * 64 + nt * 16 + col];
    #pragma unroll
    for (int mt = 0; mt < 4; ++mt)
        #pragma unroll
        for (int nt = 0; nt < 4; ++nt) {
            int n = N0 + wn * 64 + nt * 16 + col;
            #pragma unroll
            for (int reg = 0; reg < 4; ++reg) {
                int m = M0 + wm * 64 + mt * 16 + quad * 4 + reg;
                Y[(size_t)m * COUT + n] = acc[mt][nt][reg] + bb[nt];
            }
        }
}

// ---------------------------------------------------------------------------
// Qbar[b,i,:] = sum_t types[b,i,t] * Qt[b,t,i,:]
__global__ void mix_qbar(const float* __restrict__ Qt, const float* __restrict__ types,
                         float* __restrict__ Qbar)
{
    int idx = blockIdx.x * 256 + threadIdx.x;
    int bi = idx >> 6;
    int o4 = (idx & 63) * 4;
    int b = bi >> 10;
    const float* tp = types + (size_t)bi * CT;
    float t0 = tp[0], t1 = tp[1], t2 = tp[2];
    size_t nbase = ((size_t)b * CT) * CN * COUT + (size_t)(bi & 1023) * COUT + o4;
    float4 q0 = *(const float4*)(Qt + nbase);
    float4 q1 = *(const float4*)(Qt + nbase + (size_t)CN * COUT);
    float4 q2 = *(const float4*)(Qt + nbase + 2 * (size_t)CN * COUT);
    float4 o;
    o.x = t0 * q0.x + t1 * q1.x + t2 * q2.x;
    o.y = t0 * q0.y + t1 * q1.y + t2 * q2.y;
    o.z = t0 * q0.z + t1 * q1.z + t2 * q2.z;
    o.w = t0 * q0.w + t1 * q1.w + t2 * q2.w;
    *(float4*)(Qbar + (size_t)bi * COUT + o4) = o;
}

// ---------------------------------------------------------------------------
// Qr[b,r,h,i,d] = (pri[r,h]/sqrt(dk)) * sum_e rel_att[r,h,d,e]*Qbar[b,i,h*32+e]
__global__ __launch_bounds__(256) void qr3_kernel(const float* __restrict__ Qbar,
                                                  const float* __restrict__ rel_att,
                                                  const float* __restrict__ rel_pri,
                                                  unsigned short* __restrict__ Qrhi,
                                                  unsigned short* __restrict__ Qrlo)
{
    int i0 = blockIdx.x * 8;
    int rh = blockIdx.y; int r = rh >> 3, h = rh & 7;
    int b = blockIdx.z;
    __shared__ float A_s[32][33];
    __shared__ float q_s[8][32];
    int tid = threadIdx.x;
    {
        int f = tid * 4; int d = f >> 5, e = f & 31;
        float4 v = *(const float4*)(rel_att + ((size_t)rh * 32 + d) * 32 + e);
        A_s[d][e] = v.x; A_s[d][e + 1] = v.y; A_s[d][e + 2] = v.z; A_s[d][e + 3] = v.w;
        int ii = tid >> 5, ee = tid & 31;
        q_s[ii][ee] = Qbar[((size_t)b * CN + i0 + ii) * COUT + h * CDK + ee];
    }
    __syncthreads();
    int d = tid & 31, ii = tid >> 5;
    float acc = 0.f;
    #pragma unroll 8
    for (int e = 0; e < 32; ++e) acc += A_s[d][e] * q_s[ii][e];
    const float inv_sqrt = 0.17677669529663687f;
    float v = acc * rel_pri[rh] * inv_sqrt;
    unsigned short hb = f2bf(v);
    float lo = v - bf2f(hb);
    size_t oidx = ((((size_t)b * CR + r) * CH + h) * CN + i0 + ii) * CDK + d;
    Qrhi[oidx] = hb;
    Qrlo[oidx] = f2bf(lo);
}

// ---------------------------------------------------------------------------
// Fused K-prep + V-transpose:
// [0,512):    per (b,j): Kbar=sum_s ty_s*Kt_s (split) + Kty_s, h-major
// [512,2048): VT blocked: VT[((bs*CH+h)*64 + js)*512 + e*16 + j'] = Vt[bs,j,h*32+e]
__global__ __launch_bounds__(256) void prep_kv(
    const float* __restrict__ Kt, const float* __restrict__ Vt,
    const float* __restrict__ types,
    unsigned short* __restrict__ Kbh, unsigned short* __restrict__ Kbl,
    unsigned short* __restrict__ Kty, _Float16* __restrict__ VT)
{
    __shared__ float tile[32][72];
    const int bx = blockIdx.x, tid = threadIdx.x;
    if (bx < 512) {
        int b = bx >> 7, jt = bx & 127;
        int j = jt * 8 + (tid >> 5);
        int c = tid & 31;
        int h = c >> 2, d0 = (c & 3) * 8;
        const float* tp = types + ((size_t)b * CN + j) * CT;
        float kb[8];
        #pragma unroll
        for (int k = 0; k < 8; ++k) kb[k] = 0.f;
        #pragma unroll
        for (int s = 0; s < 3; ++s) {
            float ty = tp[s];
            const float* src = Kt + (((size_t)(b * 3 + s)) * CN + j) * COUT + c * 8;
            f32x4 a0 = *(const f32x4*)(src);
            f32x4 a1 = *(const f32x4*)(src + 4);
            u16x8 kt8;
            #pragma unroll
            for (int k = 0; k < 4; ++k) {
                float v0 = ty * a0[k], v1 = ty * a1[k];
                kt8[k] = f2bf(v0); kt8[4 + k] = f2bf(v1);
                kb[k] += v0; kb[4 + k] += v1;
            }
            *(u16x8*)(Kty + (((size_t)(b * 3 + s) * CH + h) * CN + j) * CDK + d0) = kt8;
        }
        u16x8 hv, lv;
        #pragma unroll
        for (int k = 0; k < 8; ++k) {
            unsigned short hb = f2bf(kb[k]);
            hv[k] = hb; lv[k] = f2bf(kb[k] - bf2f(hb));
        }
        *(u16x8*)(Kbh + (((size_t)b * CH + h) * CN + j) * CDK + d0) = hv;
        *(u16x8*)(Kbl + (((size_t)b * CH + h) * CN + j) * CDK + d0) = lv;
    } else {
        int idx2 = bx - 512;
        int bs = idx2 >> 7; int rem = idx2 & 127;
        int h = rem >> 4; int j0 = (rem & 15) * 64;
        int jj = tid >> 2, e8 = (tid & 3) * 8;
        const float* src = Vt + ((size_t)bs * CN + j0 + jj) * COUT + h * CDK + e8;
        f32x4 v0 = *(const f32x4*)(src);
        f32x4 v1 = *(const f32x4*)(src + 4);
        #pragma unroll
        for (int k = 0; k < 4; ++k) { tile[e8 + k][jj] = v0[k]; tile[e8 + 4 + k][jj] = v1[k]; }
        __syncthreads();
        int e = tid >> 3, jr = (tid & 7) * 8;
        f16x8 o;
        #pragma unroll
        for (int k = 0; k < 8; ++k) o[k] = (_Float16)tile[e][jr + k];
        int jg = j0 + jr;
        int js = jg >> 4, jp = jg & 15;
        *(f16x8*)(VT + ((size_t)(bs * CH + h) * 64 + js) * 512 + e * 16 + jp) = o;
    }
}

// ---------------------------------------------------------------------------
// MFMA flash attention v5: NO barriers, no LDS. V fragments loaded directly
// from blocked VT (coalesced 512B/wave), software-pipelined one iter ahead
// together with Kbar/coef. Waves slip freely to hide L2/L1 latency.
__global__ __launch_bounds__(256, 3) void attn5_kernel(
    const unsigned short* __restrict__ Qrhi, const unsigned short* __restrict__ Qrlo,
    const unsigned short* __restrict__ Kbh,  const unsigned short* __restrict__ Kbl,
    const unsigned short* __restrict__ Kty,
    const _Float16* __restrict__ VT,
    const float* __restrict__ coefT,
    float* __restrict__ Upart, float* __restrict__ lbuf, float* __restrict__ rowsum)
{
    const int h = blockIdx.y;
    const int z = blockIdx.z; const int b = z >> 1, part = z & 1;
    const int tid = threadIdx.x;
    const int wave = tid >> 6, lane = tid & 63;
    const int col = lane & 15, quad = lane >> 4;
    const int i = blockIdx.x * 64 + wave * 16 + col;
    const int jbase = part * 512;

    s16x8 qh[4], ql[4];
    #pragma unroll
    for (int r = 0; r < 4; ++r) {
        size_t off = ((((size_t)b * CR + r) * CH + h) * CN + i) * CDK + quad * 8;
        qh[r] = *(const s16x8*)(Qrhi + off);
        ql[r] = *(const s16x8*)(Qrlo + off);
    }

    f32x4 U[4][2];
    #pragma unroll
    for (int r = 0; r < 4; ++r) { U[r][0] = (f32x4){0.f,0.f,0.f,0.f}; U[r][1] = (f32x4){0.f,0.f,0.f,0.f}; }
    float lpart = 0.f, rspart = 0.f;

    const size_t kbbase = (((size_t)b * CH + h) * CN + col) * CDK + quad * 8;
    size_t ktbase[3];
    #pragma unroll
    for (int s = 0; s < 3; ++s)
        ktbase[s] = (((size_t)(b * 3 + s) * CH + h) * CN + col) * CDK + quad * 8;
    const size_t cfrow = ((size_t)b * CN + quad * 4) * CN + i;   // + j*CN, *4 for r
    size_t vb[3];
    #pragma unroll
    for (int s = 0; s < 3; ++s)
        vb[s] = ((size_t)((b * 3 + s) * CH + h) * 64) * 512 + col * 16 + quad * 4;

    // prologue: prefetch K/cf/V for js=0
    s16x8 p_bh[2], p_bl[2];
    f32x4 p_cf[2][4];
    f16x4 p_v0[2][3], p_v1[2][3];
    {
        const int j0 = jbase;
        p_bh[0] = *(const s16x8*)(Kbh + kbbase + (size_t)j0 * CDK);
        p_bl[0] = *(const s16x8*)(Kbl + kbbase + (size_t)j0 * CDK);
        #pragma unroll
        for (int reg = 0; reg < 4; ++reg)
            p_cf[0][reg] = *(const f32x4*)(coefT + (cfrow + (size_t)(j0 + reg) * CN) * 4);
        const size_t vo = (size_t)(j0 >> 4) * 512;
        #pragma unroll
        for (int s = 0; s < 3; ++s) {
            p_v0[0][s] = *(const f16x4*)(VT + vb[s] + vo);
            p_v1[0][s] = *(const f16x4*)(VT + vb[s] + vo + 256);
        }
    }

    #pragma unroll 2
    for (int js = 0; js < 32; ++js) {
        const int cur = js & 1, nx = cur ^ 1;
        const int j0 = jbase + js * 16;
        // current-iter Kty loads (consumed mid-iteration at Dp)
        s16x8 kt0 = *(const s16x8*)(Kty + ktbase[0] + (size_t)j0 * CDK);
        s16x8 kt1 = *(const s16x8*)(Kty + ktbase[1] + (size_t)j0 * CDK);
        s16x8 kt2 = *(const s16x8*)(Kty + ktbase[2] + (size_t)j0 * CDK);
        // next-iteration prefetches (K, cf, V)
        const int jn = jbase + ((js + 1 < 32) ? (js + 1) * 16 : js * 16);
        p_bh[nx] = *(const s16x8*)(Kbh + kbbase + (size_t)jn * CDK);
        p_bl[nx] = *(const s16x8*)(Kbl + kbbase + (size_t)jn * CDK);
        #pragma unroll
        for (int reg = 0; reg < 4; ++reg)
            p_cf[nx][reg] = *(const f32x4*)(coefT + (cfrow + (size_t)(jn + reg) * CN) * 4);
        const size_t von = (size_t)(jn >> 4) * 512;
        #pragma unroll
        for (int s = 0; s < 3; ++s) {
            p_v0[nx][s] = *(const f16x4*)(VT + vb[s] + von);
            p_v1[nx][s] = *(const f16x4*)(VT + vb[s] + von + 256);
        }

        // Dbar (precise logits path) — inputs prefetched last iteration
        f32x4 Db[4];
        #pragma unroll
        for (int r = 0; r < 4; ++r) {
            f32x4 d = {0.f, 0.f, 0.f, 0.f};
            d = __builtin_amdgcn_mfma_f32_16x16x32_bf16(p_bl[cur], qh[r], d, 0, 0, 0);
            d = __builtin_amdgcn_mfma_f32_16x16x32_bf16(p_bh[cur], ql[r], d, 0, 0, 0);
            d = __builtin_amdgcn_mfma_f32_16x16x32_bf16(p_bh[cur], qh[r], d, 0, 0, 0);
            Db[r] = d;
        }
        float P[4];
        #pragma unroll
        for (int reg = 0; reg < 4; ++reg) {
            float L = p_cf[cur][reg][0] * Db[0][reg] + p_cf[cur][reg][1] * Db[1][reg]
                    + p_cf[cur][reg][2] * Db[2][reg] + p_cf[cur][reg][3] * Db[3][reg];
            rspart += L;
            P[reg] = __expf(L);
            lpart += P[reg];
        }
        // packed P*cf per relation (reused across s)
        f16x2 pA[4], pB[4];
        #pragma unroll
        for (int r = 0; r < 4; ++r) {
            pA[r] = pk2(P[0] * p_cf[cur][0][r], P[1] * p_cf[cur][1][r]);
            pB[r] = pk2(P[2] * p_cf[cur][2][r], P[3] * p_cf[cur][3][r]);
        }
        // per-s score + PV
        #pragma unroll
        for (int s = 0; s < 3; ++s) {
            s16x8 kts = (s == 0) ? kt0 : (s == 1) ? kt1 : kt2;
            f32x4 Dp[4];
            #pragma unroll
            for (int r = 0; r < 4; ++r) {
                f32x4 d = {0.f, 0.f, 0.f, 0.f};
                Dp[r] = __builtin_amdgcn_mfma_f32_16x16x32_bf16(kts, qh[r], d, 0, 0, 0);
            }
            f16x4 v0 = p_v0[cur][s];
            f16x4 v1 = p_v1[cur][s];
            #pragma unroll
            for (int r = 0; r < 4; ++r) {
                W4 w;
                w.v2[0] = pA[r] * pk2(Dp[r][0], Dp[r][1]);
                w.v2[1] = pB[r] * pk2(Dp[r][2], Dp[r][3]);
                U[r][0] = __builtin_amdgcn_mfma_f32_16x16x16f16(v0, w.v4, U[r][0], 0, 0, 0);
                U[r][1] = __builtin_amdgcn_mfma_f32_16x16x16f16(v1, w.v4, U[r][1], 0, 0, 0);
            }
        }
    }

    float l = lpart;  l += __shfl_xor(l, 16);  l += __shfl_xor(l, 32);
    float rv = rspart; rv += __shfl_xor(rv, 16); rv += __shfl_xor(rv, 32);
    if (quad == 0) {
        lbuf[(((size_t)part * CB + b) * CH + h) * CN + i] = l;
        atomicAdd(rowsum + (size_t)b * CN + i, rv);
    }
    int itile = blockIdx.x * 4 + wave;
    size_t ub = ((((size_t)(b * CH + h) * 64 + itile) * 2 + part)) * 2048;
    #pragma unroll
    for (int r = 0; r < 4; ++r)
        #pragma unroll
        for (int eh = 0; eh < 2; ++eh)
            *(f32x4*)(Upart + ub + (size_t)(r * 2 + eh) * 256 + lane * 4) = U[r][eh];
}

// ---------------------------------------------------------------------------
// Merge j-split partials, normalize, rel_msg via MFMA, gate + gelu + split.
__global__ __launch_bounds__(256) void merge_gelu(
    const float* __restrict__ Upart, const float* __restrict__ lbuf,
    const _Float16* __restrict__ MT, const float* __restrict__ rowsum,
    unsigned short* __restrict__ Gh, unsigned short* __restrict__ Gl)
{
    const int h = blockIdx.y, b = blockIdx.z;
    const int tid = threadIdx.x;
    const int wave = tid >> 6, lane = tid & 63;
    const int col = lane & 15, quad = lane >> 4;
    const int itile = blockIdx.x * 4 + wave;
    const int i = itile * 16 + col;

    size_t ub = ((size_t)(b * CH + h) * 64 + itile) * 2 * 2048;
    f32x4 U[4][2];
    #pragma unroll
    for (int r = 0; r < 4; ++r)
        #pragma unroll
        for (int eh = 0; eh < 2; ++eh) {
            f32x4 a = *(const f32x4*)(Upart + ub + (size_t)(r * 2 + eh) * 256 + lane * 4);
            f32x4 c = *(const f32x4*)(Upart + ub + 2048 + (size_t)(r * 2 + eh) * 256 + lane * 4);
            U[r][eh] = a + c;
        }
    float l = lbuf[(((size_t)0 * CB + b) * CH + h) * CN + i]
            + lbuf[(((size_t)1 * CB + b) * CH + h) * CN + i];
    float il = 1.f / l;
    f16x4 Uh[4][2];
    #pragma unroll
    for (int r = 0; r < 4; ++r)
        #pragma unroll
        for (int eh = 0; eh < 2; ++eh) {
            Uh[r][eh][0] = (_Float16)(U[r][eh][0] * il);
            Uh[r][eh][1] = (_Float16)(U[r][eh][1] * il);
            Uh[r][eh][2] = (_Float16)(U[r][eh][2] * il);
            Uh[r][eh][3] = (_Float16)(U[r][eh][3] * il);
        }
    float rsv = rowsum[(size_t)b * CN + i];
    bool gate = rsv > 1e-6f;
    const float is2 = 0.70710678118654752f;
    #pragma unroll
    for (int eo = 0; eo < 2; ++eo) {
        f32x4 acc = {0.f, 0.f, 0.f, 0.f};
        #pragma unroll
        for (int r = 0; r < 4; ++r)
            #pragma unroll
            for (int ep = 0; ep < 2; ++ep) {
                f16x4 mt = *(const f16x4*)(MT + ((size_t)(r * 8 + h) * 32 + eo * 16 + col) * 32
                                               + ep * 16 + quad * 4);
                acc = __builtin_amdgcn_mfma_f32_16x16x16f16(mt, Uh[r][ep], acc, 0, 0, 0);
            }
        u16x4 hv, lv;
        #pragma unroll
        for (int k = 0; k < 4; ++k) {
            float x = gate ? acc[k] : 0.f;
            float g = 0.5f * x * (1.f + erff(x * is2));
            unsigned short hb = f2bf(g);
            hv[k] = hb; lv[k] = f2bf(g - bf2f(hb));
        }
        size_t off = ((size_t)b * CN + i) * COUT + h * CDK + eo * 16 + quad * 4;
        *(u16x4*)(Gh + off) = hv;
        *(u16x4*)(Gl + off) = lv;
    }
}

// ---------------------------------------------------------------------------
// gated residual + layernorm + soft-type mix; one wave per (b,i) row.
__global__ __launch_bounds__(256) void final_ln2(
    const float* __restrict__ trans, const float* __restrict__ x,
    const float* __restrict__ types, const float* __restrict__ skip,
    const float* __restrict__ gamma, const float* __restrict__ beta,
    float* __restrict__ out)
{
    int wave = threadIdx.x >> 6, lane = threadIdx.x & 63;
    int bi = blockIdx.x * 4 + wave;
    int b = bi >> 10, i = bi & 1023;
    f32x4 xo = *(const f32x4*)(x + (size_t)bi * COUT + lane * 4);
    f32x4 accum = {0.f, 0.f, 0.f, 0.f};
    const float* tp = types + (size_t)bi * CT;
    #pragma unroll 1
    for (int t = 0; t < CT; ++t) {
        float al = 1.f / (1.f + __expf(-skip[t]));
        f32x4 tr = *(const f32x4*)(trans + (((size_t)b * CT + t) * CN + i) * COUT + lane * 4);
        f32x4 res;
        float s = 0.f;
        #pragma unroll
        for (int k = 0; k < 4; ++k) { res[k] = tr[k] * al + xo[k] * (1.f - al); s += res[k]; }
        #pragma unroll
        for (int mk = 1; mk < 64; mk <<= 1) s += __shfl_xor(s, mk);
        float mu = s * (1.f / COUT);
        f32x4 dc; float s2 = 0.f;
        #pragma unroll
        for (int k = 0; k < 4; ++k) { dc[k] = res[k] - mu; s2 += dc[k] * dc[k]; }
        #pragma unroll
        for (int mk = 1; mk < 64; mk <<= 1) s2 += __shfl_xor(s2, mk);
        float inv = rsqrtf(s2 * (1.f / COUT) + 1e-5f);
        f32x4 g = *(const f32x4*)(gamma + (size_t)t * COUT + lane * 4);
        f32x4 be = *(const f32x4*)(beta + (size_t)t * COUT + lane * 4);
        float ty = tp[t];
        #pragma unroll
        for (int k = 0; k < 4; ++k) accum[k] += ty * (dc[k] * inv * g[k] + be[k]);
    }
    *(f32x4*)(out + (size_t)bi * COUT + lane * 4) = accum;
}

// ---------------------------------------------------------------------------
extern "C" void kernel_launch(void* const* d_in, const int* in_sizes, int n_in,
                              void* d_out, int out_size, void* d_ws, size_t ws_size,
                              hipStream_t stream)
{
    (void)in_sizes; (void)n_in; (void)out_size; (void)ws_size;
    const float* nf      = (const float*)d_in[0];
    const float* types   = (const float*)d_in[1];
    const float* adj     = (const float*)d_in[2];
    const float* erel    = (const float*)d_in[3];
    const float* Wq      = (const float*)d_in[4];
    const float* bq      = (const float*)d_in[5];
    const float* Wk      = (const float*)d_in[6];
    const float* bk      = (const float*)d_in[7];
    const float* Wv      = (const float*)d_in[8];
    const float* bv      = (const float*)d_in[9];
    const float* Wa      = (const float*)d_in[10];
    const float* ba      = (const float*)d_in[11];
    const float* rel_pri = (const float*)d_in[12];
    const float* rel_att = (const float*)d_in[13];
    const float* rel_msg = (const float*)d_in[14];
    const float* skip    = (const float*)d_in[15];
    const float* gamma   = (const float*)d_in[16];
    const float* beta    = (const float*)d_in[17];
    float* out = (float*)d_out;

    float* ws = (float*)d_ws;
    size_t o = 0;
    float* pool0 = ws + o; o += 3 * (size_t)CB * CT * CN * COUT;   // 9.44M f32
    float* Qt  = pool0;
    float* Ktb = pool0 + (size_t)CB * CT * CN * COUT;
    float* Vtb = pool0 + 2 * (size_t)CB * CT * CN * COUT;
    float* Qbar = ws + o; o += (size_t)CB * CN * COUT;
    float* rsb  = ws + o; o += (size_t)CB * CN;
    float* lbufp = ws + o; o += 2 * (size_t)CB * CH * CN;
    unsigned short* Qrhi = (unsigned short*)(ws + o); o += (size_t)CB * CR * CN * COUT / 2;
    unsigned short* Qrlo = (unsigned short*)(ws + o); o += (size_t)CB * CR * CN * COUT / 2;
    unsigned short* Kbh  = (unsigned short*)(ws + o); o += (size_t)CB * CH * CN * CDK / 2;
    unsigned short* Kbl  = (unsigned short*)(ws + o); o += (size_t)CB * CH * CN * CDK / 2;
    unsigned short* Kty  = (unsigned short*)(ws + o); o += (size_t)CB * CT * CH * CN * CDK / 2;
    _Float16* VTb = (_Float16*)(ws + o);              o += (size_t)CB * CT * CH * CDK * CN / 2;
    _Float16* MTb = (_Float16*)(ws + o);              o += (size_t)CR * CH * CDK * CDK / 2;
    unsigned short* Xh = (unsigned short*)(ws + o);   o += (size_t)CB * CN * COUT / 2;
    unsigned short* Xl = (unsigned short*)(ws + o);   o += (size_t)CB * CN * COUT / 2;
    unsigned short* Gh = (unsigned short*)(ws + o);   o += (size_t)CB * CN * COUT / 2;
    unsigned short* Gl = (unsigned short*)(ws + o);   o += (size_t)CB * CN * COUT / 2;
    unsigned short* WTh = (unsigned short*)(ws + o);  o += (size_t)12 * COUT * COUT / 2;
    unsigned short* WTl = (unsigned short*)(ws + o);  o += (size_t)12 * COUT * COUT / 2;
    float* coefT = ws + o; o += (size_t)CB * CN * CN * CR;   // 16.8M f32
    // overlays on pool0 (stream-ordered reuse): Upart written by attn5, dead
    // after merge_gelu; transb written by gemm(1) strictly after merge_gelu.
    float* Upart  = pool0;
    float* transb = pool0 + 3 * (size_t)CB * CN * COUT;

    prep0<<<5936, 256, 0, stream>>>(nf, Xh, Xl, Wq, Wk, Wv, Wa, WTh, WTl,
                                    rel_msg, MTb, rsb, adj, erel, coefT);
    mfma_gemm<<<dim3(8, 2, CB * 9), 256, 0, stream>>>(0, Xh, Xl, WTh, WTl,
                                                      bq, bk, bv, ba, Qt, Ktb, Vtb);
    mix_qbar<<<CB * CN * COUT / 4 / 256, 256, 0, stream>>>(Qt, types, Qbar);
    qr3_kernel<<<dim3(CN / 8, CR * CH, CB), 256, 0, stream>>>(Qbar, rel_att, rel_pri, Qrhi, Qrlo);
    prep_kv<<<2048, 256, 0, stream>>>(Ktb, Vtb, types, Kbh, Kbl, Kty, VTb);
    attn5_kernel<<<dim3(16, CH, CB * 2), 256, 0, stream>>>(Qrhi, Qrlo, Kbh, Kbl, Kty, VTb, coefT,
                                                           Upart, lbufp, rsb);
    merge_gelu<<<dim3(16, CH, CB), 256, 0, stream>>>(Upart, lbufp, MTb, rsb, Gh, Gl);
    mfma_gemm<<<dim3(8, 2, CB * CT), 256, 0, stream>>>(1, Gh, Gl, WTh, WTl,
                                                       bq, bk, bv, ba, transb, transb, transb);
    final_ln2<<<CB * CN / 4, 256, 0, stream>>>(transb, nf, types, skip, gamma, beta, out);
}

// Round 8
// 393.786 us; speedup vs baseline: 1.0756x; 1.0756x over previous
//
#include <hip/hip_runtime.h>
#include <math.h>

// Problem constants
constexpr int CB = 4, CN = 1024, CT = 3, CR = 4, CH = 8, CDK = 32, COUT = 256;

typedef __attribute__((ext_vector_type(4))) float f32x4;
typedef __attribute__((ext_vector_type(8))) short s16x8;
typedef __attribute__((ext_vector_type(2))) _Float16 f16x2;
typedef __attribute__((ext_vector_type(4))) _Float16 f16x4;
typedef __attribute__((ext_vector_type(8))) _Float16 f16x8;
typedef __attribute__((ext_vector_type(4))) unsigned short u16x4;
typedef __attribute__((ext_vector_type(8))) unsigned short u16x8;

union W4 { f16x4 v4; f16x2 v2[2]; };

__device__ inline unsigned short f2bf(float x) {
    unsigned u = __float_as_uint(x);
    unsigned r = (u + 0x7fffu + ((u >> 16) & 1u)) >> 16;
    return (unsigned short)r;
}
__device__ inline float bf2f(unsigned short b) {
    return __uint_as_float(((unsigned)b) << 16);
}
__device__ inline f16x2 pk2(float a, float b) {
    auto t = __builtin_amdgcn_cvt_pkrtz(a, b);
    f16x2 r;
    __builtin_memcpy(&r, &t, sizeof(r));
    return r;
}

// ---------------------------------------------------------------------------
// Fused independent prep work, partitioned by blockIdx.x (see round 5 notes).
__global__ __launch_bounds__(256) void prep0(
    const float* __restrict__ nf,
    unsigned short* __restrict__ Xh, unsigned short* __restrict__ Xl,
    const float* __restrict__ Wq, const float* __restrict__ Wk,
    const float* __restrict__ Wv, const float* __restrict__ Wa,
    unsigned short* __restrict__ WTh, unsigned short* __restrict__ WTl,
    const float* __restrict__ rel_msg, _Float16* __restrict__ MT,
    float* __restrict__ rs,
    const float* __restrict__ adj, const float* __restrict__ erel,
    float* __restrict__ coefT)
{
    __shared__ float smem[32 * 132];
    const int bx = blockIdx.x, tid = threadIdx.x;
    if (bx < 1024) {
        size_t idx = ((size_t)bx * 256 + tid) * 4;
        f32x4 v = *(const f32x4*)(nf + idx);
        u16x4 hv, lv;
        #pragma unroll
        for (int k = 0; k < 4; ++k) {
            unsigned short hb = f2bf(v[k]);
            hv[k] = hb; lv[k] = f2bf(v[k] - bf2f(hb));
        }
        *(u16x4*)(Xh + idx) = hv;
        *(u16x4*)(Xl + idx) = lv;
    } else if (bx < 1792) {
        int w = bx - 1024;
        int zz = w >> 6; int rem = w & 63;
        int k0 = (rem >> 3) * 32, n0 = (rem & 7) * 32;
        int t = zz % 3;
        const float* W;
        if (zz < 9) { int w3 = zz / 3; W = (w3 == 0 ? Wq : (w3 == 1 ? Wk : Wv)); }
        else W = Wa;
        W += (size_t)t * COUT * COUT;
        {
            int k = tid >> 3, n4 = (tid & 7) * 4;
            f32x4 v = *(const f32x4*)(W + (size_t)(k0 + k) * COUT + n0 + n4);
            smem[(n4 + 0) * 33 + k] = v[0]; smem[(n4 + 1) * 33 + k] = v[1];
            smem[(n4 + 2) * 33 + k] = v[2]; smem[(n4 + 3) * 33 + k] = v[3];
        }
        __syncthreads();
        int n = tid >> 3, k4 = (tid & 7) * 4;
        u16x4 hv, lv;
        #pragma unroll
        for (int j = 0; j < 4; ++j) {
            float x = smem[n * 33 + k4 + j];
            unsigned short hb = f2bf(x);
            hv[j] = hb; lv[j] = f2bf(x - bf2f(hb));
        }
        size_t off = (size_t)zz * COUT * COUT + (size_t)(n0 + n) * COUT + k0 + k4;
        *(u16x4*)(WTh + off) = hv;
        *(u16x4*)(WTl + off) = lv;
    } else if (bx < 1824) {
        int rh = bx - 1792;
        int e = tid >> 3, ep4 = (tid & 7) * 4;
        f16x4 o;
        #pragma unroll
        for (int k = 0; k < 4; ++k)
            o[k] = (_Float16)rel_msg[((size_t)rh * 32 + ep4 + k) * 32 + e];
        *(f16x4*)(MT + ((size_t)rh * 32 + e) * 32 + ep4) = o;
    } else if (bx < 1840) {
        rs[(bx - 1824) * 256 + tid] = 0.f;
    } else {
        int c = bx - 1840;
        int b = c >> 10; int rem = c & 1023;
        int i0 = (rem >> 5) * 32; int j0 = (rem & 31) * 32;
        {
            int ii = tid >> 3, jc = tid & 7;
            size_t arow = ((size_t)b * CN + i0 + ii) * CN + j0;
            f32x4 av = *(const f32x4*)(adj + arow + jc * 4);
            #pragma unroll
            for (int kk = 0; kk < 4; ++kk) {
                int j = jc * 4 + kk;
                f32x4 ev = *(const f32x4*)(erel + (arow + j) * 4);
                float a = av[kk];
                f32x4 cv;
                cv[0] = ev[0] * a; cv[1] = ev[1] * a; cv[2] = ev[2] * a; cv[3] = ev[3] * a;
                *(f32x4*)&smem[j * 132 + ii * 4] = cv;
            }
        }
        __syncthreads();
        {
            int jj = tid >> 3, ic = tid & 7;
            size_t orow = ((size_t)b * CN + j0 + jj) * CN + i0;
            #pragma unroll
            for (int kk = 0; kk < 4; ++kk)
                *(f32x4*)(coefT + (orow + ic * 4 + kk) * 4) =
                    *(const f32x4*)&smem[jj * 132 + (ic * 4 + kk) * 4];
        }
    }
}

// ---------------------------------------------------------------------------
// bf16-split MFMA GEMM: Y[1024,256] = X[1024,256] @ W[256,256] + bias.
__global__ __launch_bounds__(256) void mfma_gemm(
    int mode,
    const unsigned short* __restrict__ Ah, const unsigned short* __restrict__ Al,
    const unsigned short* __restrict__ WTh, const unsigned short* __restrict__ WTl,
    const float* __restrict__ bq, const float* __restrict__ bk,
    const float* __restrict__ bv, const float* __restrict__ ba,
    float* __restrict__ Y0, float* __restrict__ Y1, float* __restrict__ Y2)
{
    int z = blockIdx.z;
    int b, t, widx;
    const float* bias;
    float* Y;
    if (mode == 0) {
        b = z / 9; int r9 = z % 9; int w3 = r9 / 3; t = r9 % 3;
        widx = w3 * 3 + t;
        bias = (w3 == 0 ? bq : (w3 == 1 ? bk : bv)) + t * COUT;
        Y = (w3 == 0 ? Y0 : (w3 == 1 ? Y1 : Y2)) + ((size_t)b * CT + t) * CN * COUT;
    } else {
        b = z / CT; t = z % CT;
        widx = 9 + t;
        bias = ba + t * COUT;
        Y = Y0 + ((size_t)b * CT + t) * CN * COUT;
    }
    const unsigned short* Ahb = Ah + (size_t)b * CN * COUT;
    const unsigned short* Alb = Al + (size_t)b * CN * COUT;
    const unsigned short* Bhb = WTh + (size_t)widx * COUT * COUT;
    const unsigned short* Blb = WTl + (size_t)widx * COUT * COUT;

    const int M0 = blockIdx.x * 128, N0 = blockIdx.y * 128;
    __shared__ unsigned short As[2][128][40];
    __shared__ unsigned short Bs[2][128][40];
    const int tid = threadIdx.x;
    const int wave = tid >> 6, lane = tid & 63;
    const int wm = wave & 1, wn = wave >> 1;
    const int col = lane & 15, quad = lane >> 4;

    f32x4 acc[4][4];
    #pragma unroll
    for (int mt = 0; mt < 4; ++mt)
        #pragma unroll
        for (int nt = 0; nt < 4; ++nt) acc[mt][nt] = (f32x4){0.f, 0.f, 0.f, 0.f};

    for (int kt = 0; kt < COUT; kt += 32) {
        #pragma unroll
        for (int q = 0; q < 2; ++q) {
            int f = q * 256 + tid;
            int m = f >> 2, kc = (f & 3) * 8;
            *(u16x8*)&As[0][m][kc] = *(const u16x8*)(Ahb + (size_t)(M0 + m) * COUT + kt + kc);
            *(u16x8*)&As[1][m][kc] = *(const u16x8*)(Alb + (size_t)(M0 + m) * COUT + kt + kc);
            *(u16x8*)&Bs[0][m][kc] = *(const u16x8*)(Bhb + (size_t)(N0 + m) * COUT + kt + kc);
            *(u16x8*)&Bs[1][m][kc] = *(const u16x8*)(Blb + (size_t)(N0 + m) * COUT + kt + kc);
        }
        __syncthreads();
        s16x8 ah[4], al4[4], bh[4], bl4[4];
        #pragma unroll
        for (int mt = 0; mt < 4; ++mt) {
            ah[mt]  = *(const s16x8*)&As[0][wm * 64 + mt * 16 + col][quad * 8];
            al4[mt] = *(const s16x8*)&As[1][wm * 64 + mt * 16 + col][quad * 8];
        }
        #pragma unroll
        for (int nt = 0; nt < 4; ++nt) {
            bh[nt]  = *(const s16x8*)&Bs[0][wn * 64 + nt * 16 + col][quad * 8];
            bl4[nt] = *(const s16x8*)&Bs[1][wn * 64 + nt * 16 + col][quad * 8];
        }
        #pragma unroll
        for (int mt = 0; mt < 4; ++mt)
            #pragma unroll
            for (int nt = 0; nt < 4; ++nt) {
                acc[mt][nt] = __builtin_amdgcn_mfma_f32_16x16x32_bf16(al4[mt], bh[nt], acc[mt][nt], 0, 0, 0);
                acc[mt][nt] = __builtin_amdgcn_mfma_f32_16x16x32_bf16(ah[mt], bl4[nt], acc[mt][nt], 0, 0, 0);
                acc[mt][nt] = __builtin_amdgcn_mfma_f32_16x16x32_bf16(ah[mt], bh[nt], acc[mt][nt], 0, 0, 0);
            }
        __syncthreads();
    }
    float bb[4];
    #pragma unroll
    for (int nt = 0; nt < 4; ++nt) bb[nt] = bias[N0 + wn * 64 + nt * 16 + col];
    #pragma unroll
    for (int mt = 0; mt < 4; ++mt)
        #pragma unroll
        for (int nt = 0; nt < 4; ++nt) {
            int n = N0 + wn * 64 + nt * 16 + col;
            #pragma unroll
            for (int reg = 0; reg < 4; ++reg) {
                int m = M0 + wm * 64 + mt * 16 + quad * 4 + reg;
                Y[(size_t)m * COUT + n] = acc[mt][nt][reg] + bb[nt];
            }
        }
}

// ---------------------------------------------------------------------------
// Qbar[b,i,:] = sum_t types[b,i,t] * Qt[b,t,i,:]
__global__ void mix_qbar(const float* __restrict__ Qt, const float* __restrict__ types,
                         float* __restrict__ Qbar)
{
    int idx = blockIdx.x * 256 + threadIdx.x;
    int bi = idx >> 6;
    int o4 = (idx & 63) * 4;
    int b = bi >> 10;
    const float* tp = types + (size_t)bi * CT;
    float t0 = tp[0], t1 = tp[1], t2 = tp[2];
    size_t nbase = ((size_t)b * CT) * CN * COUT + (size_t)(bi & 1023) * COUT + o4;
    float4 q0 = *(const float4*)(Qt + nbase);
    float4 q1 = *(const float4*)(Qt + nbase + (size_t)CN * COUT);
    float4 q2 = *(const float4*)(Qt + nbase + 2 * (size_t)CN * COUT);
    float4 o;
    o.x = t0 * q0.x + t1 * q1.x + t2 * q2.x;
    o.y = t0 * q0.y + t1 * q1.y + t2 * q2.y;
    o.z = t0 * q0.z + t1 * q1.z + t2 * q2.z;
    o.w = t0 * q0.w + t1 * q1.w + t2 * q2.w;
    *(float4*)(Qbar + (size_t)bi * COUT + o4) = o;
}

// ---------------------------------------------------------------------------
// Qr[b,r,h,i,d] = (pri[r,h]/sqrt(dk)) * sum_e rel_att[r,h,d,e]*Qbar[b,i,h*32+e]
__global__ __launch_bounds__(256) void qr3_kernel(const float* __restrict__ Qbar,
                                                  const float* __restrict__ rel_att,
                                                  const float* __restrict__ rel_pri,
                                                  unsigned short* __restrict__ Qrhi,
                                                  unsigned short* __restrict__ Qrlo)
{
    int i0 = blockIdx.x * 8;
    int rh = blockIdx.y; int r = rh >> 3, h = rh & 7;
    int b = blockIdx.z;
    __shared__ float A_s[32][33];
    __shared__ float q_s[8][32];
    int tid = threadIdx.x;
    {
        int f = tid * 4; int d = f >> 5, e = f & 31;
        float4 v = *(const float4*)(rel_att + ((size_t)rh * 32 + d) * 32 + e);
        A_s[d][e] = v.x; A_s[d][e + 1] = v.y; A_s[d][e + 2] = v.z; A_s[d][e + 3] = v.w;
        int ii = tid >> 5, ee = tid & 31;
        q_s[ii][ee] = Qbar[((size_t)b * CN + i0 + ii) * COUT + h * CDK + ee];
    }
    __syncthreads();
    int d = tid & 31, ii = tid >> 5;
    float acc = 0.f;
    #pragma unroll 8
    for (int e = 0; e < 32; ++e) acc += A_s[d][e] * q_s[ii][e];
    const float inv_sqrt = 0.17677669529663687f;
    float v = acc * rel_pri[rh] * inv_sqrt;
    unsigned short hb = f2bf(v);
    float lo = v - bf2f(hb);
    size_t oidx = ((((size_t)b * CR + r) * CH + h) * CN + i0 + ii) * CDK + d;
    Qrhi[oidx] = hb;
    Qrlo[oidx] = f2bf(lo);
}

// ---------------------------------------------------------------------------
// Fused K-prep + V-transpose:
// [0,512):    per (b,j): Kbar=sum_s ty_s*Kt_s (split) + Kty_s, h-major
// [512,2048): VT blocked: VT[((bs*CH+h)*64 + js)*512 + e*16 + j'] = Vt[bs,j,h*32+e]
__global__ __launch_bounds__(256) void prep_kv(
    const float* __restrict__ Kt, const float* __restrict__ Vt,
    const float* __restrict__ types,
    unsigned short* __restrict__ Kbh, unsigned short* __restrict__ Kbl,
    unsigned short* __restrict__ Kty, _Float16* __restrict__ VT)
{
    __shared__ float tile[32][72];
    const int bx = blockIdx.x, tid = threadIdx.x;
    if (bx < 512) {
        int b = bx >> 7, jt = bx & 127;
        int j = jt * 8 + (tid >> 5);
        int c = tid & 31;
        int h = c >> 2, d0 = (c & 3) * 8;
        const float* tp = types + ((size_t)b * CN + j) * CT;
        float kb[8];
        #pragma unroll
        for (int k = 0; k < 8; ++k) kb[k] = 0.f;
        #pragma unroll
        for (int s = 0; s < 3; ++s) {
            float ty = tp[s];
            const float* src = Kt + (((size_t)(b * 3 + s)) * CN + j) * COUT + c * 8;
            f32x4 a0 = *(const f32x4*)(src);
            f32x4 a1 = *(const f32x4*)(src + 4);
            u16x8 kt8;
            #pragma unroll
            for (int k = 0; k < 4; ++k) {
                float v0 = ty * a0[k], v1 = ty * a1[k];
                kt8[k] = f2bf(v0); kt8[4 + k] = f2bf(v1);
                kb[k] += v0; kb[4 + k] += v1;
            }
            *(u16x8*)(Kty + (((size_t)(b * 3 + s) * CH + h) * CN + j) * CDK + d0) = kt8;
        }
        u16x8 hv, lv;
        #pragma unroll
        for (int k = 0; k < 8; ++k) {
            unsigned short hb = f2bf(kb[k]);
            hv[k] = hb; lv[k] = f2bf(kb[k] - bf2f(hb));
        }
        *(u16x8*)(Kbh + (((size_t)b * CH + h) * CN + j) * CDK + d0) = hv;
        *(u16x8*)(Kbl + (((size_t)b * CH + h) * CN + j) * CDK + d0) = lv;
    } else {
        int idx2 = bx - 512;
        int bs = idx2 >> 7; int rem = idx2 & 127;
        int h = rem >> 4; int j0 = (rem & 15) * 64;
        int jj = tid >> 2, e8 = (tid & 3) * 8;
        const float* src = Vt + ((size_t)bs * CN + j0 + jj) * COUT + h * CDK + e8;
        f32x4 v0 = *(const f32x4*)(src);
        f32x4 v1 = *(const f32x4*)(src + 4);
        #pragma unroll
        for (int k = 0; k < 4; ++k) { tile[e8 + k][jj] = v0[k]; tile[e8 + 4 + k][jj] = v1[k]; }
        __syncthreads();
        int e = tid >> 3, jr = (tid & 7) * 8;
        f16x8 o;
        #pragma unroll
        for (int k = 0; k < 8; ++k) o[k] = (_Float16)tile[e][jr + k];
        int jg = j0 + jr;
        int js = jg >> 4, jp = jg & 15;
        *(f16x8*)(VT + ((size_t)(bs * CH + h) * 64 + js) * 512 + e * 16 + jp) = o;
    }
}

// ---------------------------------------------------------------------------
// MFMA flash attention v6: block owns a 16-row i-tile; the 4 waves split the
// j-range (wave w: j-tiles w, w+4, ..., w+60) so every K/V/cf load is distinct
// per wave — no duplication, no loop barrier. Epilogue: one LDS merge of the
// 4 waves' U/l/rs partials, rel_msg MFMA in wave 0, write agg (f32).
__global__ __launch_bounds__(256, 4) void attn6_kernel(
    const unsigned short* __restrict__ Qrhi, const unsigned short* __restrict__ Qrlo,
    const unsigned short* __restrict__ Kbh,  const unsigned short* __restrict__ Kbl,
    const unsigned short* __restrict__ Kty,
    const _Float16* __restrict__ VT,
    const float* __restrict__ coefT,
    const _Float16* __restrict__ MT,
    float* __restrict__ agg, float* __restrict__ rowsum)
{
    const int h = blockIdx.y, b = blockIdx.z;
    const int tid = threadIdx.x;
    const int wave = tid >> 6, lane = tid & 63;
    const int col = lane & 15, quad = lane >> 4;
    const int i0 = blockIdx.x * 16;
    const int i = i0 + col;

    __shared__ float ldsU[4][64][36];   // [wave][lane][8 x f32x4 padded]
    __shared__ float lsh[4][16], rsh[4][16];

    s16x8 qh[4], ql[4];
    #pragma unroll
    for (int r = 0; r < 4; ++r) {
        size_t off = ((((size_t)b * CR + r) * CH + h) * CN + i) * CDK + quad * 8;
        qh[r] = *(const s16x8*)(Qrhi + off);
        ql[r] = *(const s16x8*)(Qrlo + off);
    }

    f32x4 U[4][2];
    #pragma unroll
    for (int r = 0; r < 4; ++r) { U[r][0] = (f32x4){0.f,0.f,0.f,0.f}; U[r][1] = (f32x4){0.f,0.f,0.f,0.f}; }
    float lpart = 0.f, rspart = 0.f;

    const size_t kbbase = (((size_t)b * CH + h) * CN + col) * CDK + quad * 8;
    size_t ktbase[3];
    #pragma unroll
    for (int s = 0; s < 3; ++s)
        ktbase[s] = (((size_t)(b * 3 + s) * CH + h) * CN + col) * CDK + quad * 8;
    const size_t cfrow = ((size_t)b * CN + quad * 4) * CN + i;
    size_t vb[3];
    #pragma unroll
    for (int s = 0; s < 3; ++s)
        vb[s] = ((size_t)((b * 3 + s) * CH + h) * 64) * 512 + col * 16 + quad * 4;

    // wave w handles j-tiles js = w + 4k, k in [0,16)
    #pragma unroll 1
    for (int k = 0; k < 16; ++k) {
        const int j0 = (wave + 4 * k) * 16;
        // loads for this tile (all distinct per wave)
        s16x8 kbh_ = *(const s16x8*)(Kbh + kbbase + (size_t)j0 * CDK);
        s16x8 kbl_ = *(const s16x8*)(Kbl + kbbase + (size_t)j0 * CDK);
        s16x8 kt0 = *(const s16x8*)(Kty + ktbase[0] + (size_t)j0 * CDK);
        s16x8 kt1 = *(const s16x8*)(Kty + ktbase[1] + (size_t)j0 * CDK);
        s16x8 kt2 = *(const s16x8*)(Kty + ktbase[2] + (size_t)j0 * CDK);
        f32x4 cf[4];
        #pragma unroll
        for (int reg = 0; reg < 4; ++reg)
            cf[reg] = *(const f32x4*)(coefT + (cfrow + (size_t)(j0 + reg) * CN) * 4);
        const size_t vo = (size_t)(j0 >> 4) * 512;
        f16x4 v0s[3], v1s[3];
        #pragma unroll
        for (int s = 0; s < 3; ++s) {
            v0s[s] = *(const f16x4*)(VT + vb[s] + vo);
            v1s[s] = *(const f16x4*)(VT + vb[s] + vo + 256);
        }

        // Dbar (precise logits path)
        f32x4 Db[4];
        #pragma unroll
        for (int r = 0; r < 4; ++r) {
            f32x4 d = {0.f, 0.f, 0.f, 0.f};
            d = __builtin_amdgcn_mfma_f32_16x16x32_bf16(kbl_, qh[r], d, 0, 0, 0);
            d = __builtin_amdgcn_mfma_f32_16x16x32_bf16(kbh_, ql[r], d, 0, 0, 0);
            d = __builtin_amdgcn_mfma_f32_16x16x32_bf16(kbh_, qh[r], d, 0, 0, 0);
            Db[r] = d;
        }
        float P[4];
        #pragma unroll
        for (int reg = 0; reg < 4; ++reg) {
            float L = cf[reg][0] * Db[0][reg] + cf[reg][1] * Db[1][reg]
                    + cf[reg][2] * Db[2][reg] + cf[reg][3] * Db[3][reg];
            rspart += L;
            P[reg] = __expf(L);
            lpart += P[reg];
        }
        f16x2 pA[4], pB[4];
        #pragma unroll
        for (int r = 0; r < 4; ++r) {
            pA[r] = pk2(P[0] * cf[0][r], P[1] * cf[1][r]);
            pB[r] = pk2(P[2] * cf[2][r], P[3] * cf[3][r]);
        }
        #pragma unroll
        for (int s = 0; s < 3; ++s) {
            s16x8 kts = (s == 0) ? kt0 : (s == 1) ? kt1 : kt2;
            f32x4 Dp[4];
            #pragma unroll
            for (int r = 0; r < 4; ++r) {
                f32x4 d = {0.f, 0.f, 0.f, 0.f};
                Dp[r] = __builtin_amdgcn_mfma_f32_16x16x32_bf16(kts, qh[r], d, 0, 0, 0);
            }
            #pragma unroll
            for (int r = 0; r < 4; ++r) {
                W4 w;
                w.v2[0] = pA[r] * pk2(Dp[r][0], Dp[r][1]);
                w.v2[1] = pB[r] * pk2(Dp[r][2], Dp[r][3]);
                U[r][0] = __builtin_amdgcn_mfma_f32_16x16x16f16(v0s[s], w.v4, U[r][0], 0, 0, 0);
                U[r][1] = __builtin_amdgcn_mfma_f32_16x16x16f16(v1s[s], w.v4, U[r][1], 0, 0, 0);
            }
        }
    }

    // per-wave reductions over quads (all lanes end with per-col totals)
    float l = lpart;  l += __shfl_xor(l, 16);  l += __shfl_xor(l, 32);
    float rv = rspart; rv += __shfl_xor(rv, 16); rv += __shfl_xor(rv, 32);
    // stage partials to LDS
    #pragma unroll
    for (int r = 0; r < 4; ++r)
        #pragma unroll
        for (int eh = 0; eh < 2; ++eh)
            *(f32x4*)&ldsU[wave][lane][(r * 2 + eh) * 4] = U[r][eh];
    if (quad == 0) { lsh[wave][col] = l; rsh[wave][col] = rv; }
    __syncthreads();

    if (wave == 0) {
        // merge 4 waves
        f32x4 Us[8];
        #pragma unroll
        for (int v = 0; v < 8; ++v) {
            f32x4 a0 = *(const f32x4*)&ldsU[0][lane][v * 4];
            f32x4 a1 = *(const f32x4*)&ldsU[1][lane][v * 4];
            f32x4 a2 = *(const f32x4*)&ldsU[2][lane][v * 4];
            f32x4 a3 = *(const f32x4*)&ldsU[3][lane][v * 4];
            Us[v] = (a0 + a1) + (a2 + a3);
        }
        float lt = lsh[0][col] + lsh[1][col] + lsh[2][col] + lsh[3][col];
        float il = 1.f / lt;
        f16x4 Uh[8];
        #pragma unroll
        for (int v = 0; v < 8; ++v) {
            Uh[v][0] = (_Float16)(Us[v][0] * il);
            Uh[v][1] = (_Float16)(Us[v][1] * il);
            Uh[v][2] = (_Float16)(Us[v][2] * il);
            Uh[v][3] = (_Float16)(Us[v][3] * il);
        }
        #pragma unroll
        for (int eo = 0; eo < 2; ++eo) {
            f32x4 acc = {0.f, 0.f, 0.f, 0.f};
            #pragma unroll
            for (int r = 0; r < 4; ++r)
                #pragma unroll
                for (int ep = 0; ep < 2; ++ep) {
                    f16x4 mt = *(const f16x4*)(MT + ((size_t)(r * 8 + h) * 32 + eo * 16 + col) * 32
                                                   + ep * 16 + quad * 4);
                    acc = __builtin_amdgcn_mfma_f32_16x16x16f16(mt, Uh[r * 2 + ep], acc, 0, 0, 0);
                }
            *(f32x4*)(agg + ((size_t)b * CN + i) * COUT + h * CDK + eo * 16 + quad * 4) = acc;
        }
        if (lane < 16) {
            float rt = rsh[0][lane] + rsh[1][lane] + rsh[2][lane] + rsh[3][lane];
            atomicAdd(rowsum + (size_t)b * CN + i0 + lane, rt);
        }
    }
}

// ---------------------------------------------------------------------------
// gate by rowsum, exact gelu, bf16 hi/lo split (feeds mode1 GEMM)
__global__ void gelu_split(const float* __restrict__ agg, const float* __restrict__ rowsum,
                           unsigned short* __restrict__ Gh, unsigned short* __restrict__ Gl)
{
    int idx = blockIdx.x * 256 + threadIdx.x;
    int bi = idx >> 6;
    float rsv = rowsum[bi];
    bool gate = rsv > 1e-6f;
    f32x4 v = *(const f32x4*)(agg + (size_t)idx * 4);
    const float is2 = 0.70710678118654752f;
    u16x4 hv, lv;
    #pragma unroll
    for (int k = 0; k < 4; ++k) {
        float x = gate ? v[k] : 0.f;
        float g = 0.5f * x * (1.f + erff(x * is2));
        unsigned short hb = f2bf(g);
        hv[k] = hb; lv[k] = f2bf(g - bf2f(hb));
    }
    *(u16x4*)(Gh + (size_t)idx * 4) = hv;
    *(u16x4*)(Gl + (size_t)idx * 4) = lv;
}

// ---------------------------------------------------------------------------
// gated residual + layernorm + soft-type mix; one wave per (b,i) row.
__global__ __launch_bounds__(256) void final_ln2(
    const float* __restrict__ trans, const float* __restrict__ x,
    const float* __restrict__ types, const float* __restrict__ skip,
    const float* __restrict__ gamma, const float* __restrict__ beta,
    float* __restrict__ out)
{
    int wave = threadIdx.x >> 6, lane = threadIdx.x & 63;
    int bi = blockIdx.x * 4 + wave;
    int b = bi >> 10, i = bi & 1023;
    f32x4 xo = *(const f32x4*)(x + (size_t)bi * COUT + lane * 4);
    f32x4 accum = {0.f, 0.f, 0.f, 0.f};
    const float* tp = types + (size_t)bi * CT;
    #pragma unroll 1
    for (int t = 0; t < CT; ++t) {
        float al = 1.f / (1.f + __expf(-skip[t]));
        f32x4 tr = *(const f32x4*)(trans + (((size_t)b * CT + t) * CN + i) * COUT + lane * 4);
        f32x4 res;
        float s = 0.f;
        #pragma unroll
        for (int k = 0; k < 4; ++k) { res[k] = tr[k] * al + xo[k] * (1.f - al); s += res[k]; }
        #pragma unroll
        for (int mk = 1; mk < 64; mk <<= 1) s += __shfl_xor(s, mk);
        float mu = s * (1.f / COUT);
        f32x4 dc; float s2 = 0.f;
        #pragma unroll
        for (int k = 0; k < 4; ++k) { dc[k] = res[k] - mu; s2 += dc[k] * dc[k]; }
        #pragma unroll
        for (int mk = 1; mk < 64; mk <<= 1) s2 += __shfl_xor(s2, mk);
        float inv = rsqrtf(s2 * (1.f / COUT) + 1e-5f);
        f32x4 g = *(const f32x4*)(gamma + (size_t)t * COUT + lane * 4);
        f32x4 be = *(const f32x4*)(beta + (size_t)t * COUT + lane * 4);
        float ty = tp[t];
        #pragma unroll
        for (int k = 0; k < 4; ++k) accum[k] += ty * (dc[k] * inv * g[k] + be[k]);
    }
    *(f32x4*)(out + (size_t)bi * COUT + lane * 4) = accum;
}

// ---------------------------------------------------------------------------
extern "C" void kernel_launch(void* const* d_in, const int* in_sizes, int n_in,
                              void* d_out, int out_size, void* d_ws, size_t ws_size,
                              hipStream_t stream)
{
    (void)in_sizes; (void)n_in; (void)out_size; (void)ws_size;
    const float* nf      = (const float*)d_in[0];
    const float* types   = (const float*)d_in[1];
    const float* adj     = (const float*)d_in[2];
    const float* erel    = (const float*)d_in[3];
    const float* Wq      = (const float*)d_in[4];
    const float* bq      = (const float*)d_in[5];
    const float* Wk      = (const float*)d_in[6];
    const float* bk      = (const float*)d_in[7];
    const float* Wv      = (const float*)d_in[8];
    const float* bv      = (const float*)d_in[9];
    const float* Wa      = (const float*)d_in[10];
    const float* ba      = (const float*)d_in[11];
    const float* rel_pri = (const float*)d_in[12];
    const float* rel_att = (const float*)d_in[13];
    const float* rel_msg = (const float*)d_in[14];
    const float* skip    = (const float*)d_in[15];
    const float* gamma   = (const float*)d_in[16];
    const float* beta    = (const float*)d_in[17];
    float* out = (float*)d_out;

    float* ws = (float*)d_ws;
    size_t o = 0;
    float* pool0 = ws + o; o += 3 * (size_t)CB * CT * CN * COUT;   // 9.44M f32
    float* Qt  = pool0;
    float* Ktb = pool0 + (size_t)CB * CT * CN * COUT;
    float* Vtb = pool0 + 2 * (size_t)CB * CT * CN * COUT;
    float* Qbar = ws + o; o += (size_t)CB * CN * COUT;
    float* rsb  = ws + o; o += (size_t)CB * CN;
    unsigned short* Qrhi = (unsigned short*)(ws + o); o += (size_t)CB * CR * CN * COUT / 2;
    unsigned short* Qrlo = (unsigned short*)(ws + o); o += (size_t)CB * CR * CN * COUT / 2;
    unsigned short* Kbh  = (unsigned short*)(ws + o); o += (size_t)CB * CH * CN * CDK / 2;
    unsigned short* Kbl  = (unsigned short*)(ws + o); o += (size_t)CB * CH * CN * CDK / 2;
    unsigned short* Kty  = (unsigned short*)(ws + o); o += (size_t)CB * CT * CH * CN * CDK / 2;
    _Float16* VTb = (_Float16*)(ws + o);              o += (size_t)CB * CT * CH * CDK * CN / 2;
    _Float16* MTb = (_Float16*)(ws + o);              o += (size_t)CR * CH * CDK * CDK / 2;
    unsigned short* Xh = (unsigned short*)(ws + o);   o += (size_t)CB * CN * COUT / 2;
    unsigned short* Xl = (unsigned short*)(ws + o);   o += (size_t)CB * CN * COUT / 2;
    unsigned short* Gh = (unsigned short*)(ws + o);   o += (size_t)CB * CN * COUT / 2;
    unsigned short* Gl = (unsigned short*)(ws + o);   o += (size_t)CB * CN * COUT / 2;
    unsigned short* WTh = (unsigned short*)(ws + o);  o += (size_t)12 * COUT * COUT / 2;
    unsigned short* WTl = (unsigned short*)(ws + o);  o += (size_t)12 * COUT * COUT / 2;
    float* coefT = ws + o; o += (size_t)CB * CN * CN * CR;   // 16.8M f32
    // overlays: aggb reuses Qbar (dead after qr3); transb reuses pool0 (dead
    // after prep_kv). Both writers run strictly after the overlaid readers.
    float* aggb   = Qbar;
    float* transb = pool0;

    prep0<<<5936, 256, 0, stream>>>(nf, Xh, Xl, Wq, Wk, Wv, Wa, WTh, WTl,
                                    rel_msg, MTb, rsb, adj, erel, coefT);
    mfma_gemm<<<dim3(8, 2, CB * 9), 256, 0, stream>>>(0, Xh, Xl, WTh, WTl,
                                                      bq, bk, bv, ba, Qt, Ktb, Vtb);
    mix_qbar<<<CB * CN * COUT / 4 / 256, 256, 0, stream>>>(Qt, types, Qbar);
    qr3_kernel<<<dim3(CN / 8, CR * CH, CB), 256, 0, stream>>>(Qbar, rel_att, rel_pri, Qrhi, Qrlo);
    prep_kv<<<2048, 256, 0, stream>>>(Ktb, Vtb, types, Kbh, Kbl, Kty, VTb);
    attn6_kernel<<<dim3(64, CH, CB), 256, 0, stream>>>(Qrhi, Qrlo, Kbh, Kbl, Kty, VTb, coefT,
                                                       MTb, aggb, rsb);
    gelu_split<<<CB * CN * COUT / 4 / 256, 256, 0, stream>>>(aggb, rsb, Gh, Gl);
    mfma_gemm<<<dim3(8, 2, CB * CT), 256, 0, stream>>>(1, Gh, Gl, WTh, WTl,
                                                       bq, bk, bv, ba, transb, transb, transb);
    final_ln2<<<CB * CN / 4, 256, 0, stream>>>(transb, nf, types, skip, gamma, beta, out);
}